// Round 4
// baseline (402.712 us; speedup 1.0000x reference)
//
#include <hip/hip_runtime.h>
#include <math.h>

// SimRel: out[b][c] = dot(x_b, cls_c) / max(|x_b||cls_c|, 1e-8); 1.0 if cls_c has inf.
// Round-2 structure (prep kernel for Bfrag+class norms, 2048 blocks, swapped-operand
// MFMA, vectorized stores) + OCCUPANCY/IN-FLIGHT upgrade:
//   A-staging: 5 x 1KB ring per wave (was 2 x 4KB double-buffer). 32 sub-windows,
//   issue-1 dma16 / wait vmcnt(4) per step -> SUSTAINED 4KB/wave in flight
//   (was bursty), and LDS drops 64.25 -> 52KB/block => 3 blocks/CU (12 waves/CU,
//   +50% waves, ~48KB/CU in-flight vs ~32KB). MFMA shape/layout/epilogue unchanged.

typedef __attribute__((ext_vector_type(8))) short bf16x8;   // 8 bf16 (4 VGPRs)
typedef __attribute__((ext_vector_type(4))) float f32x4;    // MFMA C/D

#define EPS 1e-8f

__device__ __forceinline__ short f2bf(float f) {
  // fp32 -> bf16 round-to-nearest-even (preserves inf)
  union { float f; unsigned u; } v; v.f = f;
  unsigned r = v.u + 0x7fffu + ((v.u >> 16) & 1u);
  return (short)(r >> 16);
}

// async 16B/lane global->LDS DMA; lds base wave-uniform, lane L lands at +L*16;
// global src address is PER-LANE.
__device__ __forceinline__ void dma16(const void* g, void* l) {
  __builtin_amdgcn_global_load_lds(
      (const __attribute__((address_space(1))) void*)g,
      (__attribute__((address_space(3))) void*)l, 16, 0, 0);
}

// ---------------- prep: Bfrag layout + class norms, once ----------------
// 4 blocks x 256 threads; block b owns classes [b*16, b*16+16).
// CN[c] = -1.0 if class c contains inf, else ||cls_c||_2 (fp32).
__global__ __launch_bounds__(256) void simrel_prep(
    const float* __restrict__ CLS, short* __restrict__ Bws,
    float* __restrict__ CNws)
{
  const int t   = threadIdx.x;
  const int c   = blockIdx.x * 16 + (t >> 4);  // class
  const int s16 = t & 15;                      // which 16-float chunk of the row
  const float4* src = (const float4*)(CLS + c * 256 + s16 * 16);
  float s = 0.f, fl = 0.f;
#pragma unroll
  for (int i = 0; i < 4; ++i) {
    float4 v = src[i];
    s += v.x * v.x + v.y * v.y + v.z * v.z + v.w * v.w;
    if (isinf(v.x) || isinf(v.y) || isinf(v.z) || isinf(v.w)) fl = 1.f;
    // MFMA fragment layout (k-slot map: slot j of quad q <-> k=(j>>2)*16+q*4+(j&3))
    const int wabs = s16 * 16 + i * 4;
    const int ks = wabs >> 5;
    const int w0 = wabs & 31;
    const int h  = w0 >> 4;
    const int qd = (w0 >> 2) & 3;
    const int lb = (qd << 4) | (c & 15);
    const int nt = c >> 4;
    *(short4*)&Bws[((ks * 4 + nt) * 64 + lb) * 8 + h * 4] =
        make_short4(f2bf(v.x), f2bf(v.y), f2bf(v.z), f2bf(v.w));
  }
  // reduce across the 16 threads sharing a class (consecutive lanes)
  s  += __shfl_xor(s, 1);  s  += __shfl_xor(s, 2);
  s  += __shfl_xor(s, 4);  s  += __shfl_xor(s, 8);
  fl += __shfl_xor(fl, 1); fl += __shfl_xor(fl, 2);
  fl += __shfl_xor(fl, 4); fl += __shfl_xor(fl, 8);
  if (s16 == 0) CNws[c] = (fl > 0.f || !isfinite(s)) ? -1.0f : sqrtf(s);
}

// ---------------- main kernel ----------------
__global__ __launch_bounds__(256, 3) void simrel_kernel(
    const float* __restrict__ X,     // Brows x 256
    const short* __restrict__ Bws,   // precomputed bf16 fragment layout (32KB)
    const float* __restrict__ CNws,  // 64 class norms (sign-encoded inf flag)
    float* __restrict__ OUT)         // Brows x 64
{
  // A: [wave][ring5][lane64][4 floats] = 20 KB (fp32, DMA-filled 1KB sub-windows)
  __shared__ __align__(16) float Abuf[4 * 5 * 256];
  // B: [ks8][nt4][lane64][8 bf16] = 32 KB
  __shared__ __align__(16) short Bfrag[8 * 4 * 64 * 8];

  const int tid  = threadIdx.x;
  const int wave = tid >> 6;
  const int lane = tid & 63;
  const int m    = lane & 15;
  const int quad = lane >> 4;

  const size_t rowbase = (size_t)blockIdx.x * 128 + (size_t)wave * 32;

  // lane's global gather base per (mti, h); sub-window w = ks*4 + mti*2 + h
  // covers floats [ks*32 + h*16 + quad*4, +4) of row rowbase + mti*16 + m.
  const float* gb[2][2];
#pragma unroll
  for (int mti = 0; mti < 2; ++mti)
#pragma unroll
    for (int h = 0; h < 2; ++h)
      gb[mti][h] = X + (rowbase + mti * 16 + m) * 256 + h * 16 + quad * 4;

  float* abase = &Abuf[wave * 5 * 256];  // wave-private 5KB ring

  // prime: sub-windows 0..3 -> ring slots 0..3 (HBM in flight during B staging)
#pragma unroll
  for (int w = 0; w < 4; ++w)
    dma16(gb[(w >> 1) & 1][w & 1] + (w >> 2) * 32, abase + w * 256);

  // stage Bfrag: linear 32KB copy, 8 x 1KB DMA per wave
  {
    const char* bs = (const char*)Bws;
    char* bd = (char*)Bfrag;
#pragma unroll
    for (int i = 0; i < 8; ++i) {
      const int off = (wave * 8 + i) * 1024;
      dma16(bs + off + lane * 16, bd + off);
    }
  }

  // class-norm table: lane needs classes nt*16 + quad*4 + r  (one float4 per nt)
  f32x4 cnq[4];
#pragma unroll
  for (int nt = 0; nt < 4; ++nt)
    cnq[nt] = *(const f32x4*)(CNws + nt * 16 + quad * 4);

  __syncthreads();  // barrier + vmcnt drain: ring slots 0-3, Bfrag, cnq resident

  f32x4 acc[2][4];
#pragma unroll
  for (int mti = 0; mti < 2; ++mti)
#pragma unroll
    for (int nt = 0; nt < 4; ++nt)
      acc[mti][nt] = (f32x4){0.f, 0.f, 0.f, 0.f};
  float ssqr[2] = {0.f, 0.f};

  bf16x8 bw[4];     // B frags for current ks (read at s%4==1, reused at s%4==3)
  float4 a0tmp;     // h=0 stash (set at even s, consumed at odd s)

#pragma unroll
  for (int s = 0; s < 32; ++s) {
    const int ks  = s >> 2;
    const int mti = (s >> 1) & 1;
    const int h   = s & 1;

    // issue sub-window s+4 into ring slot (s+4)%5 = (s-1)%5 (consumed last step)
    if (s + 4 < 32) {
      const int w = s + 4;
      dma16(gb[(w >> 1) & 1][w & 1] + (w >> 2) * 32, abase + (w % 5) * 256);
    }
    // wait for sub-window s (tail: fewer outstanding)
    if (s < 28)       asm volatile("s_waitcnt vmcnt(4)" ::: "memory");
    else if (s == 28) asm volatile("s_waitcnt vmcnt(3)" ::: "memory");
    else if (s == 29) asm volatile("s_waitcnt vmcnt(2)" ::: "memory");
    else if (s == 30) asm volatile("s_waitcnt vmcnt(1)" ::: "memory");
    else              asm volatile("s_waitcnt vmcnt(0)" ::: "memory");

    const float4 a = *(const float4*)(abase + (s % 5) * 256 + lane * 4);
    ssqr[mti] += a.x * a.x + a.y * a.y + a.z * a.z + a.w * a.w;

    if (h == 0) {
      a0tmp = a;            // k-lo half of this (ks, mti) fragment
    } else {
      if ((s & 3) == 1) {   // first h=1 of this ks: load B frags once
#pragma unroll
        for (int nt = 0; nt < 4; ++nt)
          bw[nt] = *(const bf16x8*)&Bfrag[((ks * 4 + nt) * 64 + lane) * 8];
      }
      bf16x8 af;
      af[0] = f2bf(a0tmp.x); af[1] = f2bf(a0tmp.y);
      af[2] = f2bf(a0tmp.z); af[3] = f2bf(a0tmp.w);
      af[4] = f2bf(a.x);     af[5] = f2bf(a.y);
      af[6] = f2bf(a.z);     af[7] = f2bf(a.w);
      // SWAPPED operands: D rows = classes, D cols = X-rows.
      // Lane (m,quad), reg r of acc[mti][nt] = OUT[rowbase+mti*16+m][nt*16+quad*4+r]
#pragma unroll
      for (int nt = 0; nt < 4; ++nt)
        acc[mti][nt] =
            __builtin_amdgcn_mfma_f32_16x16x32_bf16(bw[nt], af, acc[mti][nt], 0, 0, 0);
    }
  }

  // ---- epilogue: norms, divide, vectorized store ----
#pragma unroll
  for (int mti = 0; mti < 2; ++mti) {
    float s = ssqr[mti];
    s += __shfl_xor(s, 16);
    s += __shfl_xor(s, 32);
    const float xn = sqrtf(s);  // norm of row rowbase + mti*16 + m (this lane's row)
    const size_t row = rowbase + mti * 16 + m;
#pragma unroll
    for (int nt = 0; nt < 4; ++nt) {
      f32x4 o;
#pragma unroll
      for (int r = 0; r < 4; ++r) {
        const float cn = cnq[nt][r];
        const float d = fmaxf(xn * cn, EPS);
        const float v = acc[mti][nt][r] * __builtin_amdgcn_rcpf(d);
        o[r] = (cn < 0.f) ? 1.0f : v;  // sentinel: class had inf
      }
      *(f32x4*)&OUT[row * 64 + nt * 16 + quad * 4] = o;  // 16B aligned
    }
  }
}

extern "C" void kernel_launch(void* const* d_in, const int* in_sizes, int n_in,
                              void* d_out, int out_size, void* d_ws, size_t ws_size,
                              hipStream_t stream) {
  (void)n_in; (void)ws_size; (void)out_size;
  const float* X   = (const float*)d_in[0];   // inputs, fp32 B x 256
  // d_in[1] = labels (unused by the reference output)
  const float* CLS = (const float*)d_in[2];   // class_avgs, fp32 64 x 256
  float* OUT = (float*)d_out;

  short* Bws  = (short*)d_ws;                       // 32 KB bf16 fragment layout
  float* CNws = (float*)((char*)d_ws + 32768);      // 64 class norms

  const int Brows  = in_sizes[0] / 256;       // 262144
  const int blocks = Brows / 128;             // 2048 (128 rows per block)

  simrel_prep<<<4, 256, 0, stream>>>(CLS, Bws, CNws);
  simrel_kernel<<<blocks, 256, 0, stream>>>(X, Bws, CNws, OUT);
}